// Round 4
// baseline (226.214 us; speedup 1.0000x reference)
//
#include <hip/hip_runtime.h>

// y[e] = W2 . relu(W1 . concat(z[src[e]], z[dst[e]]) + b1) + b2
// N=50000, D=128, H=512, E=500000. 131 GFLOP in GEMM1.
// R11: single-barrier deep pipeline. R10 post-mortem: SQ_LDS_BANK_CONFLICT
// ==8.0M invariant across R7-R10 -> it is the global_load_lds LDS-write
// port (inherent), NOT shuffles. Remaining gap (11.8K cyc/tile vs 5.5K
// floor) = structural stalls: 2 barriers/tile, kc-loop cut in half by the
// mid-tile gather+idx block, idx loads polluting the vmcnt queue.
// Fixes:
//  - block's edge indices staged to LDS once (8KB, <=16 tiles/block):
//    vmem queue per tile is exactly {4 gathers + 1 y-store}, uniform
//    across waves; no fences/pinning needed for idx.
//  - triple-buffered ldsA (3x32KB); gathers for tile t+2 issued at TOP of
//    tile t; kc-loop = one uninterrupted 8x(4 ds_read_b128 + 16 MFMA)
//    cluster under setprio(1). vmcnt(4) at each top provably completes
//    G_t (>=4 newer ops behind it at every wait point).
//  - ONE barrier/tile: y exchange deferred one iteration through
//    double-buffered ldsY; tile t's store happens after tile t+1's
//    rendezvous barrier; store distributed per-wave (lane<8).
// Kept from R9/R10: persistent blocks, B(=W1) fully in regs (128/wave),
// operand-swapped MFMA (C row=h col=edge, in-reg h-reduce + 2 shuffles),
// source-side XOR swizzle on the gather so ds_read_b128 is conflict-free,
// b1 folded into acc init. LDS total 112.6KB -> 1 block/CU, 2 waves/SIMD.

typedef __bf16 bf16x8 __attribute__((ext_vector_type(8)));
typedef float f32x4 __attribute__((ext_vector_type(4)));

__device__ __forceinline__ unsigned short f2b(float f) {
    unsigned int u = __float_as_uint(f);
    u = (u + 0x7fffu + ((u >> 16) & 1u)) >> 16;   // RNE
    return (unsigned short)u;
}

__device__ __forceinline__ void gload_lds16(const unsigned short* g, unsigned short* l) {
    __builtin_amdgcn_global_load_lds(
        (const __attribute__((address_space(1))) unsigned int*)g,
        (__attribute__((address_space(3))) unsigned int*)l, 16, 0, 0);
}

// zb: z as bf16 [N][128].  w1s: W1 swizzled to MFMA fragment order:
// w1s[(hblk*8 + kc)*512 + lane*8 + t] = bf16(W1[hblk*16 + (lane&15)][kc*32 + (lane>>4)*8 + t])
__global__ void prep_kernel(const float* __restrict__ z, const float* __restrict__ W1,
                            unsigned short* __restrict__ zb, unsigned short* __restrict__ w1s,
                            int nz4) {
    int stride = gridDim.x * blockDim.x;
    const int nw = 256 * 64;   // (hblk*8+kc) x lane
    const int total = nz4 + nw;
    for (int idx = blockIdx.x * blockDim.x + threadIdx.x; idx < total; idx += stride) {
        if (idx < nz4) {
            float4 v = ((const float4*)z)[idx];
            ushort4 o;
            o.x = f2b(v.x); o.y = f2b(v.y); o.z = f2b(v.z); o.w = f2b(v.w);
            ((ushort4*)zb)[idx] = o;
        } else {
            int u = idx - nz4;            // 0..16383
            int lane = u & 63;
            int blk  = u >> 6;            // hblk*8 + kc
            int h  = (blk >> 3) * 16 + (lane & 15);
            int kb = (blk & 7) * 32 + (lane >> 4) * 8;
            const float* src = W1 + h * 256 + kb;
            ushort4 o0, o1;
            float4 v0 = *(const float4*)(src);
            float4 v1 = *(const float4*)(src + 4);
            o0.x = f2b(v0.x); o0.y = f2b(v0.y); o0.z = f2b(v0.z); o0.w = f2b(v0.w);
            o1.x = f2b(v1.x); o1.y = f2b(v1.y); o1.z = f2b(v1.z); o1.w = f2b(v1.w);
            ushort4* dst = (ushort4*)(w1s + u * 8);
            dst[0] = o0; dst[1] = o1;
        }
    }
}

__global__ __launch_bounds__(512, 2)
void edge_mlp_kernel(const int* __restrict__ ei, const unsigned short* __restrict__ zb,
                     const unsigned short* __restrict__ w1s,
                     const float* __restrict__ b1, const float* __restrict__ W2,
                     const float* __restrict__ b2p, float* __restrict__ out,
                     int E, int ntiles) {
    __shared__ unsigned short ldsA[3][64 * 256];  // 96 KB, triple-buffered A tiles
    __shared__ int   ldsIdx[16 * 128];            // 8 KB: [it][side*64 + m]
    __shared__ float ldsY[2][512];                // 4 KB: parity-buffered y exchange
    __shared__ float ldsB1[512];                  // 2 KB staged b1

    const int tid  = threadIdx.x;
    const int lane = tid & 63;
    const int w    = tid >> 6;        // 0..7 : 64-h slice of H=512
    const int l15  = lane & 15;
    const int l4   = lane >> 4;
    const int G    = gridDim.x;
    const int t0   = blockIdx.x;
    if (t0 >= ntiles) return;

    // ---- stage ALL of this block's edge indices into LDS (<=16 tiles) ----
    // NOTE: assumes ceil(ntiles/G) <= 16 (holds: 7813 tiles / 512 blocks).
    {
        const int itq = tid >> 7;      // 0..3
        const int sd  = (tid >> 6) & 1;
        const int m   = tid & 63;
        #pragma unroll
        for (int p = 0; p < 4; ++p) {
            int itt = p * 4 + itq;
            int t = t0 + itt * G;
            int e = t * 64 + m;
            if (t >= ntiles || e >= E) e = E - 1;   // clamp: data unused or tail
            ldsIdx[itt * 128 + sd * 64 + m] = ei[sd * E + e];
        }
    }
    ldsB1[tid] = b1[tid];

    // ---- persistent W1: wave w holds hblk w*4..w*4+3, full K, in regs ----
    uint4 breg[4][8];                 // 128 regs
    #pragma unroll
    for (int j = 0; j < 4; ++j)
        #pragma unroll
        for (int kc = 0; kc < 8; ++kc)
            breg[j][kc] = *(const uint4*)(w1s + (((w * 4 + j) * 8 + kc) << 9) + lane * 8);

    // w2 per lane: h = w*64 + j*16 + l4*4 + r  -> f32x4 per j (16 regs)
    f32x4 w2v[4];
    #pragma unroll
    for (int j = 0; j < 4; ++j)
        w2v[j] = *(const f32x4*)&W2[w * 64 + j * 16 + l4 * 4];
    const float b2v = b2p[0];

    const int side = (lane >> 4) & 1;
    const int rsub = lane >> 5;

    asm volatile("s_waitcnt vmcnt(0) lgkmcnt(0)" ::: "memory");  // idx/b1/breg staged
    __builtin_amdgcn_s_barrier();
    asm volatile("" ::: "memory");

    // gather: instr q covers rows m=(w*8+q*2)+rsub; lane L writes LDS slot L&31
    // of the row pair; source slot pre-swizzled s' = l15 ^ (m&7) so the read
    // side (slot ^ (row&7)) is conflict-free.
#define ISSUE_GATHER(ITIDX, BUF)                                              \
    do {                                                                      \
        _Pragma("unroll")                                                     \
        for (int q_ = 0; q_ < 4; ++q_) {                                      \
            int m_   = w * 8 + q_ * 2 + rsub;                                 \
            int row_ = ldsIdx[(ITIDX) * 128 + side * 64 + m_];                \
            int s15_ = l15 ^ (m_ & 7);                                        \
            gload_lds16(zb + (row_ << 7) + (s15_ << 3),                       \
                        &ldsA[BUF][(w * 8 + q_ * 2) << 8]);                   \
        }                                                                     \
    } while (0)

    // prologue: fill buf0 (T0) and buf1 (T1); 8 gathers outstanding
    ISSUE_GATHER(0, 0);
    ISSUE_GATHER(1, 1);

    int tprev = 0, pprev = 0, it = 0;
    for (int t = t0; t < ntiles; t += G, ++it) {
        const int p = it & 1;
        // G_t complete: >=4 vmem ops are newer than G_t's last gather at
        // every wait point (G_{t+1}[4] (+ y-store)). Single barrier per tile.
        asm volatile("s_waitcnt vmcnt(4)" ::: "memory");
        asm volatile("s_waitcnt lgkmcnt(0)" ::: "memory");
        __builtin_amdgcn_s_barrier();
        asm volatile("" ::: "memory");

        // deferred store of tile t-1's y (visible via the barrier above)
        if (it > 0 && lane < 8) {
            int e = tprev * 64 + w * 8 + lane;
            if (e < E) {
                float v = b2v;
                #pragma unroll
                for (int k = 0; k < 8; ++k) v += ldsY[pprev][k * 64 + w * 8 + lane];
                out[e] = v;
            }
        }

        // issue gathers for tile t+2 into buf[(it+2)%3] (read last iter, free)
        {
            int itg = it + 2; if (itg > 15) itg = 15;   // clamped: result unused
            ISSUE_GATHER(itg, (it + 2) % 3);
        }
        asm volatile("" ::: "memory");

        const unsigned short* bufc = &ldsA[it % 3][0];

        // acc init = b1 (acc ends as W1.x + b1); C row=h, col=edge
        f32x4 acc[4][4];                  // [edge-tile i][h-tile j]
        {
            f32x4 b1t[4];
            #pragma unroll
            for (int j = 0; j < 4; ++j)
                b1t[j] = *(const f32x4*)&ldsB1[w * 64 + j * 16 + l4 * 4];
            #pragma unroll
            for (int i = 0; i < 4; i++)
                #pragma unroll
                for (int j = 0; j < 4; j++) acc[i][j] = b1t[j];
        }

        const int swz = l15 & 7;
        __builtin_amdgcn_s_setprio(1);
        #pragma unroll
        for (int kc = 0; kc < 8; ++kc) {
            bf16x8 a[4];
            #pragma unroll
            for (int i = 0; i < 4; ++i)
                a[i] = *(const bf16x8*)&bufc[((l15 + 16 * i) << 8) + ((((kc << 2) + l4) ^ swz) << 3)];
            #pragma unroll
            for (int i = 0; i < 4; ++i)
                #pragma unroll
                for (int j = 0; j < 4; ++j)
                    acc[i][j] = __builtin_amdgcn_mfma_f32_16x16x32_bf16(
                        *(const bf16x8*)&breg[j][kc], a[i], acc[i][j], 0, 0, 0);
        }
        __builtin_amdgcn_s_setprio(0);

        // epilogue: y[e] = sum_h relu(acc)*w2; in-reg over (j,r) + 2 shuffles
        #pragma unroll
        for (int i = 0; i < 4; i++) {
            float s = 0.f;
            #pragma unroll
            for (int j = 0; j < 4; j++)
                #pragma unroll
                for (int r = 0; r < 4; r++)
                    s = fmaf(fmaxf(acc[i][j][r], 0.f), w2v[j][r], s);
            s += __shfl_xor(s, 16);
            s += __shfl_xor(s, 32);
            if (l4 == 0) ldsY[p][w * 64 + i * 16 + l15] = s;
        }

        tprev = t; pprev = p;
    }

    // drain: store the last tile's y
    asm volatile("s_waitcnt lgkmcnt(0)" ::: "memory");
    __builtin_amdgcn_s_barrier();
    asm volatile("" ::: "memory");
    if (lane < 8) {
        int e = tprev * 64 + w * 8 + lane;
        if (e < E) {
            float v = b2v;
            #pragma unroll
            for (int k = 0; k < 8; ++k) v += ldsY[pprev][k * 64 + w * 8 + lane];
            out[e] = v;
        }
    }
#undef ISSUE_GATHER
}

extern "C" void kernel_launch(void* const* d_in, const int* in_sizes, int n_in,
                              void* d_out, int out_size, void* d_ws, size_t ws_size,
                              hipStream_t stream) {
    const float* z  = (const float*)d_in[0];
    const int*   ei = (const int*)d_in[1];
    const float* W1 = (const float*)d_in[2];
    const float* b1 = (const float*)d_in[3];
    const float* W2 = (const float*)d_in[4];
    const float* b2 = (const float*)d_in[5];
    float* out = (float*)d_out;

    const int E  = in_sizes[1] / 2;   // 500000
    const int NZ = in_sizes[0];       // 6400000 = N*D

    unsigned short* zb  = (unsigned short*)d_ws;       // 12.8 MB
    unsigned short* w1s = zb + NZ;                     // 256 KB (swizzled W1)

    prep_kernel<<<2048, 256, 0, stream>>>(z, W1, zb, w1s, NZ / 4);

    const int ntiles = (E + 63) / 64;                  // 7813
    int grid = ntiles < 512 ? ntiles : 512;            // persistent, <=16 tiles/block
    edge_mlp_kernel<<<grid, 512, 0, stream>>>(ei, zb, w1s, b1, W2, b2, out, E, ntiles);
}